// Round 1
// baseline (494.882 us; speedup 1.0000x reference)
//
#include <hip/hip_runtime.h>

// TT embedding bag: indices decompose as idx = d0*2500 + d1*50 + d2, each digit < 50.
// pair = idx/50 = d0*50+d1 (2500 distinct), d2 = idx%50.
// emb[kk*8+z] = sum_r2 t[pair][kk][r2] * core2[d2][r2*8+z],  kk in [0,16), z in [0,8)
// t[pair][x*4+y][s] = sum_r core0[d0][x*32+r] * core1[d1][r*128 + y*32 + s]

#define PAIRS 2500
#define TROW 512  // 16*32 floats per pair

__global__ __launch_bounds__(256) void build_t_kernel(
    const float* __restrict__ core0, const float* __restrict__ core1,
    float* __restrict__ t_table) {
  __shared__ float c0[128];
  __shared__ float c1[4096];
  const int pair = blockIdx.x;
  const int d0 = pair / 50, d1 = pair - d0 * 50;
  const int tid = threadIdx.x;

  // stage core1 row (16KB) and core0 row (512B) in LDS, coalesced float4 loads
  const float4* src1 = reinterpret_cast<const float4*>(core1 + (size_t)d1 * 4096);
  float4* dst1 = reinterpret_cast<float4*>(c1);
  for (int i = tid; i < 1024; i += 256) dst1[i] = src1[i];
  if (tid < 32) {
    reinterpret_cast<float4*>(c0)[tid] =
        reinterpret_cast<const float4*>(core0 + (size_t)d0 * 128)[tid];
  }
  __syncthreads();

#pragma unroll
  for (int q = 0; q < 2; ++q) {
    const int o = tid + q * 256;      // output element in [0,512)
    const int kk = o >> 5;            // 16 rows
    const int s = o & 31;             // 32 cols (r2)
    const int x = kk >> 2, y = kk & 3;
    float acc = 0.f;
#pragma unroll
    for (int r = 0; r < 32; ++r)
      acc += c0[x * 32 + r] * c1[r * 128 + y * 32 + s];
    t_table[(size_t)pair * TROW + o] = acc;
  }
}

__global__ __launch_bounds__(128) void bag_kernel(
    const int* __restrict__ indices, const int* __restrict__ offsets,
    const int* __restrict__ cached_indices, const int* __restrict__ cached_offsets,
    const float* __restrict__ core2, const float* __restrict__ cache_table,
    const float* __restrict__ t_table, float* __restrict__ out) {
  const int b = blockIdx.x;
  const int tid = threadIdx.x;        // output dim k = kk*8 + z
  const int kk = tid >> 3;
  const int z = tid & 7;

  float acc = 0.f;

  // --- TT part ---
  const int start = offsets[b];
  const int end = offsets[b + 1];
  for (int p = start; p < end; ++p) {
    const int idx = indices[p];
    const int pair = idx / 50;
    const int d2 = idx - pair * 50;
    const float* __restrict__ trow = t_table + (size_t)pair * TROW + kk * 32;
    const float* __restrict__ g2 = core2 + (size_t)d2 * 256 + z;  // stride 8 over r2
    float s = 0.f;
#pragma unroll
    for (int r = 0; r < 32; r += 4) {
      const float4 tv = *reinterpret_cast<const float4*>(trow + r);
      s += tv.x * g2[(r + 0) * 8];
      s += tv.y * g2[(r + 1) * 8];
      s += tv.z * g2[(r + 2) * 8];
      s += tv.w * g2[(r + 3) * 8];
    }
    acc += s;
  }

  // --- cached part: coalesced row gather ---
  const int cs = cached_offsets[b];
  const int ce = cached_offsets[b + 1];
  for (int p = cs; p < ce; ++p) {
    const int ci = cached_indices[p];
    acc += cache_table[(size_t)ci * 128 + tid];
  }

  out[(size_t)b * 128 + tid] = acc;
}

extern "C" void kernel_launch(void* const* d_in, const int* in_sizes, int n_in,
                              void* d_out, int out_size, void* d_ws, size_t ws_size,
                              hipStream_t stream) {
  const int* indices        = (const int*)d_in[0];
  const int* offsets        = (const int*)d_in[1];
  const int* cached_indices = (const int*)d_in[2];
  const int* cached_offsets = (const int*)d_in[3];
  const float* core0        = (const float*)d_in[4];
  const float* core1        = (const float*)d_in[5];
  const float* core2        = (const float*)d_in[6];
  const float* cache_table  = (const float*)d_in[7];
  float* out = (float*)d_out;

  float* t_table = (float*)d_ws;  // 2500*512*4 = 5,120,000 bytes

  build_t_kernel<<<PAIRS, 256, 0, stream>>>(core0, core1, t_table);

  const int num_bags = 4096;
  bag_kernel<<<num_bags, 128, 0, stream>>>(indices, offsets, cached_indices,
                                           cached_offsets, core2, cache_table,
                                           t_table, out);
}